// Round 11
// baseline (1499.190 us; speedup 1.0000x reference)
//
#include <hip/hip_runtime.h>

#define TOL 1e-6f
#define NITER 101
#define H 256
#define W 256
#define HW 65536
#define NBLK 256
#define TPB 256

typedef unsigned long long ull;

// ---- workspace layout (float offsets) ----
#define STRIP_F 768                  // floats per block per buffer (3ch x 256)
#define STRIPBUF (NBLK * STRIP_F)
#define WS_CTRL (2 * STRIPBUF)
#define CTRL_F 8192
// ctrl: lvalA[8][256]@512 lvalB[8][256]@2560  (per-XCD partials, L2)
//       uints @4608: lcnt x*16 | icnt@144 | xcnt@160+16x
//       lbcA  ull@(u+576)+(x*4+s)*8   (32 lines, 4 sub-lines/XCD)
//       lbcB  ull@(u+1088)+(x*4+s)*8  (32 lines)
//       slotA ull@(u+1600)+(par*8+x)*8  (16 lines: parity ping-pong x 8 XCD)
//       slotB ull@(u+1856)+(par*8+x)*8  (16 lines)

#define LD_AG(p)    __hip_atomic_load((p), __ATOMIC_RELAXED, __HIP_MEMORY_SCOPE_AGENT)
#define ST_AG(p,v)  __hip_atomic_store((p), (v), __ATOMIC_RELAXED, __HIP_MEMORY_SCOPE_AGENT)

// Opaque identity operands: WITHOUT these, InstCombine rewrites
// atomicrmw add p,0 -> load atomic (same scope); a workgroup-scope atomic
// load is served from the spinner's stale L1 -> infinite spin (the R4/R5
// hang). RMWs execute at >= L2 and can never be L1-stale.
__device__ __forceinline__ unsigned opq0u() {
    unsigned z; asm volatile("s_mov_b32 %0, 0" : "=s"(z)); return z;
}
__device__ __forceinline__ ull opq0ull() {
    return ((ull)opq0u() << 32) | (ull)opq0u();
}
__device__ __forceinline__ float opq0f() { return __uint_as_float(opq0u()); }

// ---------------------------------------------------------------------------
// fused DOUBLE reduce + broadcast + barrier.
// R11: MASTERLESS. Each XCD leader posts {rnd, xcd_partial} to its slot line
// (parity ping-pong), then sweep-polls all present XCDs' slots and sums in
// fixed XCD order (deterministic). Replaces R10's 5 serialized agent-scope
// round trips (gval add -> gcnt -> master read -> bcast store -> leader poll)
// with ~1.5 (post is fire-and-forget; poll discovers the last poster).
// Parity slots are safe by the 2-barrier-separation induction (a leader can
// only reuse a parity slot after every other leader has read the old value).
// ---------------------------------------------------------------------------
__device__ __forceinline__ float2 frb2(float va, float vb, unsigned rnd, float* ctrl,
                                       unsigned my_xcc, unsigned xn, unsigned pres) {
    __shared__ float redA_[4], redB_[4], out_[2];
    asm volatile("s_waitcnt vmcnt(0)" ::: "memory");
    #pragma unroll
    for (int off = 32; off; off >>= 1) {
        va += __shfl_down(va, off, 64);
        vb += __shfl_down(vb, off, 64);
    }
    const int lane = threadIdx.x & 63, wid = threadIdx.x >> 6;
    if (lane == 0) { redA_[wid] = va; redB_[wid] = vb; }
    __syncthreads();
    if (threadIdx.x == 0) {
        const float pa = redA_[0] + redA_[1] + redA_[2] + redA_[3];
        const float pb = redB_[0] + redB_[1] + redB_[2] + redB_[3];
        const unsigned sub = (blockIdx.x >> 3) & 3u;   // spinner sub-line
        float* lvalA = ctrl + 512  + my_xcc * 256;
        float* lvalB = ctrl + 2560 + my_xcc * 256;
        unsigned* cu = (unsigned*)(ctrl + 4608);
        ull* lbcA   = (ull*)(cu + 576);
        ull* lbcB   = (ull*)(cu + 1088);
        ull* slotA  = (ull*)(cu + 1600);
        ull* slotB  = (ull*)(cu + 1856);
        __hip_atomic_fetch_add(lvalA + rnd, pa, __ATOMIC_RELAXED, __HIP_MEMORY_SCOPE_WORKGROUP);
        __hip_atomic_fetch_add(lvalB + rnd, pb, __ATOMIC_RELAXED, __HIP_MEMORY_SCOPE_WORKGROUP);
        asm volatile("s_waitcnt vmcnt(0)" ::: "memory");
        unsigned a = __hip_atomic_fetch_add(cu + my_xcc * 16, 1u,
                         __ATOMIC_RELAXED, __HIP_MEMORY_SCOPE_WORKGROUP);
        ull pkA, pkB;
        if (a == rnd * xn - 1u) {                       // XCD leader (last arriver)
            float la = __hip_atomic_fetch_add(lvalA + rnd, opq0f(),
                           __ATOMIC_RELAXED, __HIP_MEMORY_SCOPE_WORKGROUP);
            float lb = __hip_atomic_fetch_add(lvalB + rnd, opq0f(),
                           __ATOMIC_RELAXED, __HIP_MEMORY_SCOPE_WORKGROUP);
            const unsigned par = (rnd & 1u) * 8u;
            __hip_atomic_store(slotA + (par + my_xcc) * 8,
                               ((ull)rnd << 32) | (ull)__float_as_uint(la),
                               __ATOMIC_RELAXED, __HIP_MEMORY_SCOPE_AGENT);
            __hip_atomic_store(slotB + (par + my_xcc) * 8,
                               ((ull)rnd << 32) | (ull)__float_as_uint(lb),
                               __ATOMIC_RELAXED, __HIP_MEMORY_SCOPE_AGENT);
            // sweep all present XCDs in fixed order (deterministic sum)
            float ta = 0.f, tb = 0.f;
            for (unsigned x = 0; x < 8; ++x) {
                if (!(pres & (1u << x))) continue;
                ull pk;
                for (;;) {
                    pk = __hip_atomic_fetch_add(slotA + (par + x) * 8, opq0ull(),
                             __ATOMIC_RELAXED, __HIP_MEMORY_SCOPE_AGENT);
                    if ((unsigned)(pk >> 32) >= rnd) break;
                    __builtin_amdgcn_s_sleep(1);
                }
                ta += __uint_as_float((unsigned)(pk & 0xffffffffull));
            }
            for (unsigned x = 0; x < 8; ++x) {
                if (!(pres & (1u << x))) continue;
                ull pk;
                for (;;) {
                    pk = __hip_atomic_fetch_add(slotB + (par + x) * 8, opq0ull(),
                             __ATOMIC_RELAXED, __HIP_MEMORY_SCOPE_AGENT);
                    if ((unsigned)(pk >> 32) >= rnd) break;
                    __builtin_amdgcn_s_sleep(1);
                }
                tb += __uint_as_float((unsigned)(pk & 0xffffffffull));
            }
            pkA = ((ull)rnd << 32) | (ull)__float_as_uint(ta);
            pkB = ((ull)rnd << 32) | (ull)__float_as_uint(tb);
            // fan out to 4 sub-lines per channel (B first, then A)
            #pragma unroll
            for (int s = 0; s < 4; ++s)
                __hip_atomic_store(lbcB + (my_xcc * 4 + s) * 8, pkB,
                                   __ATOMIC_RELAXED, __HIP_MEMORY_SCOPE_WORKGROUP);
            #pragma unroll
            for (int s = 0; s < 4; ++s)
                __hip_atomic_store(lbcA + (my_xcc * 4 + s) * 8, pkA,
                                   __ATOMIC_RELAXED, __HIP_MEMORY_SCOPE_WORKGROUP);
        } else {
            ull* mylA = lbcA + (my_xcc * 4 + sub) * 8;
            ull* mylB = lbcB + (my_xcc * 4 + sub) * 8;
            for (;;) {
                pkA = __hip_atomic_fetch_add(mylA, opq0ull(),
                          __ATOMIC_RELAXED, __HIP_MEMORY_SCOPE_WORKGROUP);
                if ((unsigned)(pkA >> 32) >= rnd) break;
                __builtin_amdgcn_s_sleep(2);
            }
            for (;;) {
                pkB = __hip_atomic_fetch_add(mylB, opq0ull(),
                          __ATOMIC_RELAXED, __HIP_MEMORY_SCOPE_WORKGROUP);
                if ((unsigned)(pkB >> 32) >= rnd) break;
                __builtin_amdgcn_s_sleep(1);
            }
        }
        out_[0] = __uint_as_float((unsigned)(pkA & 0xffffffffull));
        out_[1] = __uint_as_float((unsigned)(pkB & 0xffffffffull));
    }
    __syncthreads();
    return make_float2(out_[0], out_[1]);
}

// halo ring (36x36 minus 32x32 core): 272 positions
__device__ __forceinline__ void ring_pos(int t, int& eh, int& ew) {
    if (t < 72)       { eh = t / 36;                 ew = t - (t / 36) * 36; }
    else if (t < 144) { const int u = t - 72;  eh = 34 + u / 36; ew = u - (u / 36) * 36; }
    else              { const int u = t - 144; eh = 2 + (u >> 2);
                        const int c2 = u & 3;  ew = (c2 < 2) ? c2 : c2 + 32; }
}

// ---------------------------------------------------------------------------
// composite PT(P(.)) as 25-tap K2 over dext + border fixups (proven R7).
// ---------------------------------------------------------------------------
__device__ __forceinline__ float4 conv_k2(const float* dext, int row, int wb,
                                          int h0, int w0,
                                          const float* K2sh,
                                          const float* Ctop, const float* Cbot,
                                          const float* CLf, const float* CLt, const float* CLb,
                                          const float* CRf, const float* CRt, const float* CRb)
{
    float q[4] = {0.f, 0.f, 0.f, 0.f};
    float w2s[8], cL[5], cR[5];
    const float* base = dext + row * 36 + wb;
    #pragma unroll
    for (int A = 0; A < 5; ++A) {
        const float4 lo = *(const float4*)(base + A * 36);
        const float4 hi = *(const float4*)(base + A * 36 + 4);
        const float w8[8] = {lo.x, lo.y, lo.z, lo.w, hi.x, hi.y, hi.z, hi.w};
        #pragma unroll
        for (int cc = 0; cc < 4; ++cc) {
            float s = q[cc];
            #pragma unroll
            for (int Bq = 0; Bq < 5; ++Bq)
                s += K2sh[A * 5 + Bq] * w8[cc + Bq];
            q[cc] = s;
        }
        if (A == 2) {
            #pragma unroll
            for (int u = 0; u < 8; ++u) w2s[u] = w8[u];
        }
        cL[A] = w8[2]; cR[A] = w8[5];
    }
    const int gh = h0 + row, gwb = w0 + wb;
    if (gh == 0) {
        #pragma unroll
        for (int cc = 0; cc < 4; ++cc)
            #pragma unroll
            for (int Bq = 0; Bq < 5; ++Bq)
                q[cc] -= Ctop[Bq] * w2s[cc + Bq];
    }
    if (gh == 255) {
        #pragma unroll
        for (int cc = 0; cc < 4; ++cc)
            #pragma unroll
            for (int Bq = 0; Bq < 5; ++Bq)
                q[cc] -= Cbot[Bq] * w2s[cc + Bq];
    }
    if (gwb == 0) {
        const float* C = (gh == 0) ? CLt : ((gh == 255) ? CLb : CLf);
        #pragma unroll
        for (int A = 0; A < 5; ++A) q[0] -= C[A] * cL[A];
    }
    if (gwb == 252) {
        const float* C = (gh == 0) ? CRt : ((gh == 255) ? CRb : CRf);
        #pragma unroll
        for (int A = 0; A < 5; ++A) q[3] -= C[A] * cR[A];
    }
    return make_float4(q[0], q[1], q[2], q[3]);
}

extern "C" __global__ void __launch_bounds__(TPB)
cg_persistent(const float* __restrict__ mask, const float* __restrict__ y,
              const float* __restrict__ z, const float* __restrict__ bet,
              const float* __restrict__ rho_p, const float* __restrict__ kern,
              float* __restrict__ x_out, float* __restrict__ ws)
{
    __shared__ float ksh[27];
    __shared__ __align__(16) float dext[36 * 36];
    __shared__ float m_ring[3][272];
    __shared__ float r_ring[3][272];
    __shared__ float q_ring[3][272];
    __shared__ float sstage[STRIP_F];
    __shared__ int   ringsrc[272];
    __shared__ float K2sh[25];
    __shared__ float Ctop[5], Cbot[5];
    __shared__ float CLf[5], CLt[5], CLb[5], CRf[5], CRt[5], CRb[5];

    float* strip = ws;
    float* ctrl  = ws + WS_CTRL;

    const int tid = threadIdx.x;
    const int T  = blockIdx.x;
    const int bi = T >> 6;
    const int h0 = ((T >> 3) & 7) << 5;
    const int w0 = (T & 7) << 5;
    const int row = tid >> 3;
    const int wb  = (tid & 7) << 2;
    const int roffb = (h0 + row) * W + (w0 + wb);

    unsigned xcc_raw;
    asm volatile("s_getreg_b32 %0, hwreg(HW_REG_XCC_ID)" : "=s"(xcc_raw));
    const unsigned my_xcc = xcc_raw & 7u;

    unsigned xn = 0, pres = 0;
    unsigned* cu = (unsigned*)(ctrl + 4608);
    if (tid == 0) {
        __hip_atomic_fetch_add(cu + 160 + 16 * my_xcc, 1u,
                               __ATOMIC_RELAXED, __HIP_MEMORY_SCOPE_AGENT);
        __hip_atomic_fetch_add(cu + 144, 1u,
                               __ATOMIC_RELAXED, __HIP_MEMORY_SCOPE_AGENT);
    }

    if (tid < 27) ksh[tid] = kern[tid];
    const float rho = rho_p[0];

    float m_[3][4], x_[3][4], r_[3][4], p_[3][4], q_[3][4], w_[3][4];
    #pragma unroll
    for (int c = 0; c < 3; ++c) {
        const float4 mv = *(const float4*)(mask + (bi * 3 + c) * HW + roffb);
        m_[c][0] = mv.x; m_[c][1] = mv.y; m_[c][2] = mv.z; m_[c][3] = mv.w;
    }

    // m_ring + iteration-invariant ring -> neighbor-strip index table
    for (int t = tid; t < 272; t += TPB) {
        int eh, ew; ring_pos(t, eh, ew);
        const int gh = h0 + eh - 2, gw = w0 + ew - 2;
        const bool valid = (unsigned)gh < (unsigned)H && (unsigned)gw < (unsigned)W;
        int src = -1;
        if (valid) {
            const int tr = gh >> 5, tc = gw >> 5;
            const int Tn = (bi << 6) | (tr << 3) | tc;
            const int lh = gh & 31, lw = gw & 31;
            int idx;
            if (tr != (h0 >> 5)) idx = (lh >= 30) ? 64 + (lh - 30) * 32 + lw : lh * 32 + lw;
            else                 idx = (lw >= 30) ? 192 + lh * 2 + (lw - 30) : 128 + lh * 2 + lw;
            src = Tn * STRIP_F + idx;
        }
        ringsrc[t] = src;
        #pragma unroll
        for (int c = 0; c < 3; ++c) {
            m_ring[c][t] = valid ? mask[(bi * 3 + c) * HW + gh * W + gw] : 0.f;
            r_ring[c][t] = 0.f;
            q_ring[c][t] = 0.f;
        }
    }

    // ---- I-a: fill dext from y
    for (int e = tid; e < 1296; e += TPB) {
        const int eh = e / 36, ew = e - eh * 36;
        const int gh = h0 + eh - 2, gw = w0 + ew - 2;
        dext[e] = ((unsigned)gh < (unsigned)H && (unsigned)gw < (unsigned)W)
                      ? y[bi * HW + gh * W + gw] : 0.f;
    }
    __syncthreads();

    // ---- composite tables
    if (tid < 25) {
        const int A = tid / 5, Bq = tid % 5;
        float s = 0.f;
        for (int o = 0; o < 3; ++o)
            for (int i = (A > 2 ? A - 2 : 0); i <= (A < 2 ? A : 2); ++i)
                for (int j = (Bq > 2 ? Bq - 2 : 0); j <= (Bq < 2 ? Bq : 2); ++j)
                    s += ksh[o * 9 + (A - i) * 3 + (Bq - j)] * ksh[o * 9 + (2 - i) * 3 + (2 - j)];
        K2sh[tid] = s;
    } else if (tid < 35) {
        const int Bq = (tid - 25) % 5;
        const int krow = (tid < 30) ? 6 : 0;
        float s = 0.f;
        for (int o = 0; o < 3; ++o)
            for (int j = (Bq > 2 ? Bq - 2 : 0); j <= (Bq < 2 ? Bq : 2); ++j)
                s += ksh[o * 9 + krow + (Bq - j)] * ksh[o * 9 + krow + (2 - j)];
        if (tid < 30) Ctop[Bq] = s; else Cbot[Bq] = s;
    } else if (tid < 65) {
        const int u = tid - 35;
        const int side = u / 15;
        const int v = (u % 15) / 5;
        const int A = u % 5;
        const int kcol = side ? 0 : 2;
        int ilo = (A > 2 ? A - 2 : 0), ihi = (A < 2 ? A : 2);
        if (v == 1 && ilo < 1) ilo = 1;
        if (v == 2 && ihi > 1) ihi = 1;
        float s = 0.f;
        for (int o = 0; o < 3; ++o)
            for (int i = ilo; i <= ihi; ++i)
                s += ksh[o * 9 + (A - i) * 3 + kcol] * ksh[o * 9 + (2 - i) * 3 + kcol];
        float* dst = side ? (v == 0 ? CRf : v == 1 ? CRt : CRb)
                          : (v == 0 ? CLf : v == 1 ? CLt : CLb);
        dst[A] = s;
    }
    __syncthreads();

#define STAGE_BORDER(SRC)                                                          \
    _Pragma("unroll")                                                              \
    for (int c = 0; c < 3; ++c) {                                                  \
        if (row < 2) {                                                             \
            _Pragma("unroll")                                                      \
            for (int cc = 0; cc < 4; ++cc)                                         \
                sstage[c * 256 + row * 32 + wb + cc] = SRC[c][cc];                 \
        }                                                                          \
        if (row >= 30) {                                                           \
            _Pragma("unroll")                                                      \
            for (int cc = 0; cc < 4; ++cc)                                         \
                sstage[c * 256 + 64 + (row - 30) * 32 + wb + cc] = SRC[c][cc];     \
        }                                                                          \
        if (wb == 0)  { sstage[c * 256 + 128 + row * 2]     = SRC[c][0];           \
                        sstage[c * 256 + 128 + row * 2 + 1] = SRC[c][1]; }         \
        if (wb == 28) { sstage[c * 256 + 192 + row * 2]     = SRC[c][2];           \
                        sstage[c * 256 + 192 + row * 2 + 1] = SRC[c][3]; }         \
    }

    // I-a: q0conv = PT(P(y)); b = m*q0conv + rho*(z-bet); x = b; publish b -> buf0
    {
        const float4 qv = conv_k2(dext, row, wb, h0, w0, K2sh, Ctop, Cbot,
                                  CLf, CLt, CLb, CRf, CRt, CRb);
        const float qa[4] = {qv.x, qv.y, qv.z, qv.w};
        #pragma unroll
        for (int c = 0; c < 3; ++c) {
            const int gi = (bi * 3 + c) * HW + roffb;
            const float4 zv = *(const float4*)(z + gi);
            const float4 bv = *(const float4*)(bet + gi);
            const float zz[4] = {zv.x, zv.y, zv.z, zv.w};
            const float bb[4] = {bv.x, bv.y, bv.z, bv.w};
            #pragma unroll
            for (int cc = 0; cc < 4; ++cc)
                x_[c][cc] = m_[c][cc] * qa[cc] + rho * (zz[cc] - bb[cc]);
        }
    }
    STAGE_BORDER(x_)
    __syncthreads();
    for (int t = tid; t < STRIP_F; t += TPB)
        ST_AG(strip + T * STRIP_F + t, sstage[t]);

    // finish population count -> xn, pres (opaque RMW polls)
    if (tid == 0) {
        while (__hip_atomic_fetch_add(cu + 144, opq0u(), __ATOMIC_RELAXED,
                                      __HIP_MEMORY_SCOPE_AGENT) < (unsigned)NBLK)
            __builtin_amdgcn_s_sleep(32);
        pres = 0;
        #pragma unroll
        for (int i = 0; i < 8; ++i) {
            unsigned c = __hip_atomic_fetch_add(cu + 160 + 16 * i, opq0u(),
                             __ATOMIC_RELAXED, __HIP_MEMORY_SCOPE_AGENT);
            if (c > 0u) pres |= (1u << i);
        }
        xn = __hip_atomic_fetch_add(cu + 160 + 16 * my_xcc, opq0u(),
                 __ATOMIC_RELAXED, __HIP_MEMORY_SCOPE_AGENT);
    }
    unsigned rnd = 1;
    frb2(0.f, 0.f, rnd++, ctrl, my_xcc, xn, pres);   // b strips visible

    // ---- I-b: d0 = sum m*b; r0 = b - A(b); gamma0; publish r0 -> buf1
    {
        float* dp = dext + (row + 2) * 36 + 2 + wb;
        #pragma unroll
        for (int cc = 0; cc < 4; ++cc)
            dp[cc] = m_[0][cc] * x_[0][cc] + m_[1][cc] * x_[1][cc] + m_[2][cc] * x_[2][cc];
    }
    for (int t = tid; t < 272; t += TPB) {
        int eh, ew; ring_pos(t, eh, ew);
        const int src = ringsrc[t];
        float s = 0.f;
        if (src >= 0) {
            #pragma unroll
            for (int c = 0; c < 3; ++c)
                s += m_ring[c][t] * LD_AG(strip + src + c * 256);
        }
        dext[eh * 36 + ew] = s;
    }
    __syncthreads();
    float gsum0 = 0.f;
    {
        const float4 qv = conv_k2(dext, row, wb, h0, w0, K2sh, Ctop, Cbot,
                                  CLf, CLt, CLb, CRf, CRt, CRb);
        const float qa[4] = {qv.x, qv.y, qv.z, qv.w};
        #pragma unroll
        for (int c = 0; c < 3; ++c)
            #pragma unroll
            for (int cc = 0; cc < 4; ++cc) {
                const float b = x_[c][cc];
                const float rv = b - (rho * b + m_[c][cc] * qa[cc]);
                r_[c][cc] = rv; p_[c][cc] = rv;
                gsum0 += rv * rv;
            }
    }
    STAGE_BORDER(r_)
    __syncthreads();
    for (int t = tid; t < STRIP_F; t += TPB)
        ST_AG(strip + STRIPBUF + T * STRIP_F + t, sstage[t]);

    float gamma = frb2(gsum0, 0.f, rnd++, ctrl, my_xcc, xn, pres).x;  // r0 visible

    // r_ring <- r0 halo
    for (int t = tid; t < 272; t += TPB) {
        const int src = ringsrc[t];
        if (src >= 0) {
            #pragma unroll
            for (int c = 0; c < 3; ++c)
                r_ring[c][t] = LD_AG(strip + STRIPBUF + src + c * 256);
        }
    }

    // ---- I-c: w0 = A(r0); delta0 = r0.w0; q = w0; publish w0 -> buf0
    {
        float* dp = dext + (row + 2) * 36 + 2 + wb;
        #pragma unroll
        for (int cc = 0; cc < 4; ++cc)
            dp[cc] = m_[0][cc] * r_[0][cc] + m_[1][cc] * r_[1][cc] + m_[2][cc] * r_[2][cc];
    }
    for (int t = tid; t < 272; t += TPB) {
        int eh, ew; ring_pos(t, eh, ew);
        float s = 0.f;
        #pragma unroll
        for (int c = 0; c < 3; ++c) s += m_ring[c][t] * r_ring[c][t];
        dext[eh * 36 + ew] = s;
    }
    __syncthreads();
    float dsum0 = 0.f;
    {
        const float4 qv = conv_k2(dext, row, wb, h0, w0, K2sh, Ctop, Cbot,
                                  CLf, CLt, CLb, CRf, CRt, CRb);
        const float qa[4] = {qv.x, qv.y, qv.z, qv.w};
        #pragma unroll
        for (int c = 0; c < 3; ++c)
            #pragma unroll
            for (int cc = 0; cc < 4; ++cc) {
                const float wv = rho * r_[c][cc] + m_[c][cc] * qa[cc];
                q_[c][cc] = wv;
                dsum0 += r_[c][cc] * wv;
            }
    }
    STAGE_BORDER(q_)
    __syncthreads();
    for (int t = tid; t < STRIP_F; t += TPB)
        ST_AG(strip + T * STRIP_F + t, sstage[t]);

    const float delta0 = frb2(dsum0, 0.f, rnd++, ctrl, my_xcc, xn, pres).x; // w0 vis

    // q_ring <- w0 halo
    for (int t = tid; t < 272; t += TPB) {
        const int src = ringsrc[t];
        if (src >= 0) {
            #pragma unroll
            for (int c = 0; c < 3; ++c)
                q_ring[c][t] = LD_AG(strip + src + c * 256);
        }
    }
    float alpha = (gamma >= TOL) ? (gamma / delta0) : 0.f;

    // ---- CG loop: ONE frb2 per iteration (Chronopoulos-Gear CG).
    // beta = gamma'/gamma (both MEASURED -> no recurrence feedback, the R8
    // failure mode); alpha' = gamma'/(delta' - beta*gamma'/alpha).
    for (int j = 0; j < NITER; ++j) {
        const bool active = (gamma >= TOL);

        if (active) {
            #pragma unroll
            for (int c = 0; c < 3; ++c)
                #pragma unroll
                for (int cc = 0; cc < 4; ++cc) {
                    x_[c][cc] += alpha * p_[c][cc];
                    r_[c][cc] -= alpha * q_[c][cc];
                }
            for (int t = tid; t < 272; t += TPB) {
                #pragma unroll
                for (int c = 0; c < 3; ++c)
                    r_ring[c][t] -= alpha * q_ring[c][t];
            }
        }

        // w = A(r): d = sum m*r (core + ring)
        {
            float* dp = dext + (row + 2) * 36 + 2 + wb;
            #pragma unroll
            for (int cc = 0; cc < 4; ++cc)
                dp[cc] = m_[0][cc] * r_[0][cc] + m_[1][cc] * r_[1][cc] + m_[2][cc] * r_[2][cc];
        }
        for (int t = tid; t < 272; t += TPB) {
            int eh, ew; ring_pos(t, eh, ew);
            float s = 0.f;
            #pragma unroll
            for (int c = 0; c < 3; ++c) s += m_ring[c][t] * r_ring[c][t];
            dext[eh * 36 + ew] = s;
        }
        __syncthreads();
        float gsum = 0.f, dsum = 0.f;
        {
            const float4 qv = conv_k2(dext, row, wb, h0, w0, K2sh, Ctop, Cbot,
                                      CLf, CLt, CLb, CRf, CRt, CRb);
            const float qa[4] = {qv.x, qv.y, qv.z, qv.w};
            #pragma unroll
            for (int c = 0; c < 3; ++c)
                #pragma unroll
                for (int cc = 0; cc < 4; ++cc) {
                    const float rv = r_[c][cc];
                    const float wv = rho * rv + m_[c][cc] * qa[cc];
                    w_[c][cc] = wv;
                    gsum += rv * rv;
                    dsum += rv * wv;
                }
        }
        // publish w strips (pre-frb; frb is the separating barrier).
        STAGE_BORDER(w_)
        __syncthreads();
        float* gb = strip + ((j + 1) & 1) * STRIPBUF;
        for (int t = tid; t < STRIP_F; t += TPB)
            ST_AG(gb + T * STRIP_F + t, sstage[t]);

        const float2 gd = frb2(gsum, dsum, rnd++, ctrl, my_xcc, xn, pres);

        if (active) {
            const float gp = gd.x, dp = gd.y;
            const float beta = gp / gamma;
            const float alphan = gp / (dp - beta * gp / alpha);
            #pragma unroll
            for (int c = 0; c < 3; ++c)
                #pragma unroll
                for (int cc = 0; cc < 4; ++cc) {
                    p_[c][cc] = r_[c][cc] + beta * p_[c][cc];
                    q_[c][cc] = w_[c][cc] + beta * q_[c][cc];
                }
            for (int t = tid; t < 272; t += TPB) {
                const int src = ringsrc[t];
                if (src >= 0) {
                    #pragma unroll
                    for (int c = 0; c < 3; ++c) {
                        const float wn = LD_AG(gb + src + c * 256);
                        q_ring[c][t] = wn + beta * q_ring[c][t];
                    }
                }
            }
            gamma = gp;
            alpha = alphan;
        }
    }

    #pragma unroll
    for (int c = 0; c < 3; ++c)
        *(float4*)(x_out + (bi * 3 + c) * HW + roffb) =
            make_float4(x_[c][0], x_[c][1], x_[c][2], x_[c][3]);
}

extern "C" void kernel_launch(void* const* d_in, const int* in_sizes, int n_in,
                              void* d_out, int out_size, void* d_ws, size_t ws_size,
                              hipStream_t stream)
{
    const float* mask = (const float*)d_in[0];
    const float* y    = (const float*)d_in[1];
    const float* z    = (const float*)d_in[2];
    const float* bet  = (const float*)d_in[3];
    const float* rho  = (const float*)d_in[4];
    const float* kern = (const float*)d_in[5];
    float* x  = (float*)d_out;
    float* ws = (float*)d_ws;

    hipMemsetAsync(ws + WS_CTRL, 0, CTRL_F * sizeof(float), stream);

    void* args[] = { (void*)&mask, (void*)&y, (void*)&z, (void*)&bet,
                     (void*)&rho, (void*)&kern, (void*)&x, (void*)&ws };
    hipLaunchCooperativeKernel((void*)cg_persistent, dim3(NBLK), dim3(TPB),
                               args, 0, stream);
}

// Round 13
// 1059.618 us; speedup vs baseline: 1.4148x; 1.4148x over previous
//
#include <hip/hip_runtime.h>

#define TOL 1e-6f
#define NITER 101
#define H 256
#define W 256
#define HW 65536
#define NBLK 256
#define TPB 256

typedef unsigned long long ull;

// ---- workspace layout (float offsets) ----
#define STRIP_F 768                  // floats per block per buffer (3ch x 256)
#define STRIPBUF (NBLK * STRIP_F)
#define WS_CTRL (2 * STRIPBUF)
#define CTRL_F 16384                 // 64 KB control region (memset at launch)
// ctrl: gvalA[256]@0 gvalB[256]@256 lvalA[8][256]@512 lvalB[8][256]@2560
//       uints @4608: lcnt x*16 | gcnt@128 | icnt@144 | xcnt@160+16x
//       bcastA ull@(u+320)+x*8  bcastB ull@(u+448)+x*8
//       lbcA  ull@(u+576)+(x*4+s)*8   lbcB ull@(u+1088)+(x*4+s)*8
//       flags ull@(u+2048)+(par*256+blk)*8   (512 lines, 64B stride)

#define LD_AG(p)    __hip_atomic_load((p), __ATOMIC_RELAXED, __HIP_MEMORY_SCOPE_AGENT)
#define ST_AG(p,v)  __hip_atomic_store((p), (v), __ATOMIC_RELAXED, __HIP_MEMORY_SCOPE_AGENT)

// Opaque identity operands: WITHOUT these, InstCombine rewrites
// atomicrmw add p,0 -> load atomic (same scope); a workgroup-scope atomic
// load is served from the spinner's stale L1 -> infinite spin (the R4/R5
// hang). RMWs execute at >= L2 and can never be L1-stale.
__device__ __forceinline__ unsigned opq0u() {
    unsigned z; asm volatile("s_mov_b32 %0, 0" : "=s"(z)); return z;
}
__device__ __forceinline__ ull opq0ull() {
    return ((ull)opq0u() << 32) | (ull)opq0u();
}
__device__ __forceinline__ float opq0f() { return __uint_as_float(opq0u()); }

struct FrbTok { unsigned role; ull pkA, pkB; };   // 0=spin 1=leader 2=master

// ---------------------------------------------------------------------------
// R10-proven frb2 protocol, split into arrive (prefix) + wait (polls only).
// (Exercised on HW in R12 through init + 101 iters; R12's failure was the
// PIPECG recurrence, not this protocol.)
// ---------------------------------------------------------------------------
__device__ __forceinline__ FrbTok frb2_arrive(float va, float vb, unsigned rnd,
                                              float* ctrl, unsigned my_xcc,
                                              unsigned xn, unsigned ng) {
    __shared__ float redA_[4], redB_[4];
    asm volatile("s_waitcnt vmcnt(0)" ::: "memory");
    #pragma unroll
    for (int off = 32; off; off >>= 1) {
        va += __shfl_down(va, off, 64);
        vb += __shfl_down(vb, off, 64);
    }
    const int lane = threadIdx.x & 63, wid = threadIdx.x >> 6;
    if (lane == 0) { redA_[wid] = va; redB_[wid] = vb; }
    __syncthreads();
    FrbTok tk; tk.role = 0u; tk.pkA = 0ull; tk.pkB = 0ull;
    if (threadIdx.x == 0) {
        const float pa = redA_[0] + redA_[1] + redA_[2] + redA_[3];
        const float pb = redB_[0] + redB_[1] + redB_[2] + redB_[3];
        float* gvalA = ctrl;
        float* gvalB = ctrl + 256;
        float* lvalA = ctrl + 512  + my_xcc * 256;
        float* lvalB = ctrl + 2560 + my_xcc * 256;
        unsigned* cu = (unsigned*)(ctrl + 4608);
        ull* bcastA = (ull*)(cu + 320);
        ull* bcastB = (ull*)(cu + 448);
        ull* lbcA   = (ull*)(cu + 576);
        ull* lbcB   = (ull*)(cu + 1088);
        __hip_atomic_fetch_add(lvalA + rnd, pa, __ATOMIC_RELAXED, __HIP_MEMORY_SCOPE_WORKGROUP);
        __hip_atomic_fetch_add(lvalB + rnd, pb, __ATOMIC_RELAXED, __HIP_MEMORY_SCOPE_WORKGROUP);
        asm volatile("s_waitcnt vmcnt(0)" ::: "memory");
        unsigned a = __hip_atomic_fetch_add(cu + my_xcc * 16, 1u,
                         __ATOMIC_RELAXED, __HIP_MEMORY_SCOPE_WORKGROUP);
        if (a == rnd * xn - 1u) {                   // XCD leader (last arriver)
            tk.role = 1u;
            float la = __hip_atomic_fetch_add(lvalA + rnd, opq0f(),
                           __ATOMIC_RELAXED, __HIP_MEMORY_SCOPE_WORKGROUP);
            float lb = __hip_atomic_fetch_add(lvalB + rnd, opq0f(),
                           __ATOMIC_RELAXED, __HIP_MEMORY_SCOPE_WORKGROUP);
            __hip_atomic_fetch_add(gvalA + rnd, la, __ATOMIC_RELAXED, __HIP_MEMORY_SCOPE_AGENT);
            __hip_atomic_fetch_add(gvalB + rnd, lb, __ATOMIC_RELAXED, __HIP_MEMORY_SCOPE_AGENT);
            asm volatile("s_waitcnt vmcnt(0)" ::: "memory");
            unsigned g = __hip_atomic_fetch_add(cu + 128, 1u,
                             __ATOMIC_RELAXED, __HIP_MEMORY_SCOPE_AGENT);
            if (g == rnd * ng - 1u) {               // global master: finish now
                tk.role = 2u;
                float ta = __hip_atomic_fetch_add(gvalA + rnd, opq0f(),
                               __ATOMIC_RELAXED, __HIP_MEMORY_SCOPE_AGENT);
                float tb = __hip_atomic_fetch_add(gvalB + rnd, opq0f(),
                               __ATOMIC_RELAXED, __HIP_MEMORY_SCOPE_AGENT);
                tk.pkA = ((ull)rnd << 32) | (ull)__float_as_uint(ta);
                tk.pkB = ((ull)rnd << 32) | (ull)__float_as_uint(tb);
                #pragma unroll
                for (int xx = 0; xx < 8; ++xx)
                    __hip_atomic_store(bcastB + xx * 8, tk.pkB,
                                       __ATOMIC_RELAXED, __HIP_MEMORY_SCOPE_AGENT);
                #pragma unroll
                for (int xx = 0; xx < 8; ++xx)
                    __hip_atomic_store(bcastA + xx * 8, tk.pkA,
                                       __ATOMIC_RELAXED, __HIP_MEMORY_SCOPE_AGENT);
                #pragma unroll
                for (int s = 0; s < 4; ++s)
                    __hip_atomic_store(lbcB + (my_xcc * 4 + s) * 8, tk.pkB,
                                       __ATOMIC_RELAXED, __HIP_MEMORY_SCOPE_WORKGROUP);
                #pragma unroll
                for (int s = 0; s < 4; ++s)
                    __hip_atomic_store(lbcA + (my_xcc * 4 + s) * 8, tk.pkA,
                                       __ATOMIC_RELAXED, __HIP_MEMORY_SCOPE_WORKGROUP);
            }
        }
    }
    return tk;
}

__device__ __forceinline__ float2 frb2_wait(FrbTok tk, unsigned rnd, float* ctrl,
                                            unsigned my_xcc) {
    __shared__ float outw_[2];
    if (threadIdx.x == 0) {
        unsigned* cu = (unsigned*)(ctrl + 4608);
        ull* bcastA = (ull*)(cu + 320);
        ull* bcastB = (ull*)(cu + 448);
        ull* lbcA   = (ull*)(cu + 576);
        ull* lbcB   = (ull*)(cu + 1088);
        const unsigned sub = (blockIdx.x >> 3) & 3u;
        ull pkA, pkB;
        if (tk.role == 2u) { pkA = tk.pkA; pkB = tk.pkB; }
        else if (tk.role == 1u) {
            for (;;) {                                  // private line: sleepless
                pkA = __hip_atomic_fetch_add(bcastA + my_xcc * 8, opq0ull(),
                          __ATOMIC_RELAXED, __HIP_MEMORY_SCOPE_AGENT);
                if ((unsigned)(pkA >> 32) >= rnd) break;
            }
            for (;;) {
                pkB = __hip_atomic_fetch_add(bcastB + my_xcc * 8, opq0ull(),
                          __ATOMIC_RELAXED, __HIP_MEMORY_SCOPE_AGENT);
                if ((unsigned)(pkB >> 32) >= rnd) break;
            }
            #pragma unroll
            for (int s = 0; s < 4; ++s)
                __hip_atomic_store(lbcB + (my_xcc * 4 + s) * 8, pkB,
                                   __ATOMIC_RELAXED, __HIP_MEMORY_SCOPE_WORKGROUP);
            #pragma unroll
            for (int s = 0; s < 4; ++s)
                __hip_atomic_store(lbcA + (my_xcc * 4 + s) * 8, pkA,
                                   __ATOMIC_RELAXED, __HIP_MEMORY_SCOPE_WORKGROUP);
        } else {
            ull* mylA = lbcA + (my_xcc * 4 + sub) * 8;
            ull* mylB = lbcB + (my_xcc * 4 + sub) * 8;
            for (;;) {
                pkA = __hip_atomic_fetch_add(mylA, opq0ull(),
                          __ATOMIC_RELAXED, __HIP_MEMORY_SCOPE_WORKGROUP);
                if ((unsigned)(pkA >> 32) >= rnd) break;
                __builtin_amdgcn_s_sleep(2);
            }
            for (;;) {
                pkB = __hip_atomic_fetch_add(mylB, opq0ull(),
                          __ATOMIC_RELAXED, __HIP_MEMORY_SCOPE_WORKGROUP);
                if ((unsigned)(pkB >> 32) >= rnd) break;
                __builtin_amdgcn_s_sleep(1);
            }
        }
        outw_[0] = __uint_as_float((unsigned)(pkA & 0xffffffffull));
        outw_[1] = __uint_as_float((unsigned)(pkB & 0xffffffffull));
    }
    __syncthreads();
    return make_float2(outw_[0], outw_[1]);
}

// halo ring (36x36 minus 32x32 core): 272 positions
__device__ __forceinline__ void ring_pos(int t, int& eh, int& ew) {
    if (t < 72)       { eh = t / 36;                 ew = t - (t / 36) * 36; }
    else if (t < 144) { const int u = t - 72;  eh = 34 + u / 36; ew = u - (u / 36) * 36; }
    else              { const int u = t - 144; eh = 2 + (u >> 2);
                        const int c2 = u & 3;  ew = (c2 < 2) ? c2 : c2 + 32; }
}

// ---------------------------------------------------------------------------
// composite PT(P(.)) as 25-tap K2 over dext + border fixups (proven R7).
// ---------------------------------------------------------------------------
__device__ __forceinline__ float4 conv_k2(const float* dext, int row, int wb,
                                          int h0, int w0,
                                          const float* K2sh,
                                          const float* Ctop, const float* Cbot,
                                          const float* CLf, const float* CLt, const float* CLb,
                                          const float* CRf, const float* CRt, const float* CRb)
{
    float q[4] = {0.f, 0.f, 0.f, 0.f};
    float w2s[8], cL[5], cR[5];
    const float* base = dext + row * 36 + wb;
    #pragma unroll
    for (int A = 0; A < 5; ++A) {
        const float4 lo = *(const float4*)(base + A * 36);
        const float4 hi = *(const float4*)(base + A * 36 + 4);
        const float w8[8] = {lo.x, lo.y, lo.z, lo.w, hi.x, hi.y, hi.z, hi.w};
        #pragma unroll
        for (int cc = 0; cc < 4; ++cc) {
            float s = q[cc];
            #pragma unroll
            for (int Bq = 0; Bq < 5; ++Bq)
                s += K2sh[A * 5 + Bq] * w8[cc + Bq];
            q[cc] = s;
        }
        if (A == 2) {
            #pragma unroll
            for (int u = 0; u < 8; ++u) w2s[u] = w8[u];
        }
        cL[A] = w8[2]; cR[A] = w8[5];
    }
    const int gh = h0 + row, gwb = w0 + wb;
    if (gh == 0) {
        #pragma unroll
        for (int cc = 0; cc < 4; ++cc)
            #pragma unroll
            for (int Bq = 0; Bq < 5; ++Bq)
                q[cc] -= Ctop[Bq] * w2s[cc + Bq];
    }
    if (gh == 255) {
        #pragma unroll
        for (int cc = 0; cc < 4; ++cc)
            #pragma unroll
            for (int Bq = 0; Bq < 5; ++Bq)
                q[cc] -= Cbot[Bq] * w2s[cc + Bq];
    }
    if (gwb == 0) {
        const float* C = (gh == 0) ? CLt : ((gh == 255) ? CLb : CLf);
        #pragma unroll
        for (int A = 0; A < 5; ++A) q[0] -= C[A] * cL[A];
    }
    if (gwb == 252) {
        const float* C = (gh == 0) ? CRt : ((gh == 255) ? CRb : CRf);
        #pragma unroll
        for (int A = 0; A < 5; ++A) q[3] -= C[A] * cR[A];
    }
    return make_float4(q[0], q[1], q[2], q[3]);
}

extern "C" __global__ void __launch_bounds__(TPB)
cg_persistent(const float* __restrict__ mask, const float* __restrict__ y,
              const float* __restrict__ z, const float* __restrict__ bet,
              const float* __restrict__ rho_p, const float* __restrict__ kern,
              float* __restrict__ x_out, float* __restrict__ ws)
{
    __shared__ float ksh[27];
    __shared__ __align__(16) float dext[36 * 36];
    __shared__ float m_ring[3][272];
    __shared__ float r_ring[3][272];
    __shared__ float q_ring[3][272];
    __shared__ float u_ring[3][272];
    __shared__ float sstage[STRIP_F];
    __shared__ int   ringsrc[272];
    __shared__ int   nbl[8];
    __shared__ int   nn_sh;
    __shared__ float K2sh[25];
    __shared__ float Ctop[5], Cbot[5];
    __shared__ float CLf[5], CLt[5], CLb[5], CRf[5], CRt[5], CRb[5];

    float* strip = ws;
    float* ctrl  = ws + WS_CTRL;

    const int tid = threadIdx.x;
    const int T  = blockIdx.x;
    const int bi = T >> 6;
    const int h0 = ((T >> 3) & 7) << 5;
    const int w0 = (T & 7) << 5;
    const int row = tid >> 3;
    const int wb  = (tid & 7) << 2;
    const int roffb = (h0 + row) * W + (w0 + wb);

    unsigned xcc_raw;
    asm volatile("s_getreg_b32 %0, hwreg(HW_REG_XCC_ID)" : "=s"(xcc_raw));
    const unsigned my_xcc = xcc_raw & 7u;

    unsigned xn = 0, ng = 0;
    unsigned* cu = (unsigned*)(ctrl + 4608);
    ull* flg = (ull*)(cu + 2048);
    if (tid == 0) {
        __hip_atomic_fetch_add(cu + 160 + 16 * my_xcc, 1u,
                               __ATOMIC_RELAXED, __HIP_MEMORY_SCOPE_AGENT);
        __hip_atomic_fetch_add(cu + 144, 1u,
                               __ATOMIC_RELAXED, __HIP_MEMORY_SCOPE_AGENT);
        int n = 0;
        const int tr0 = (T >> 3) & 7, tc0 = T & 7;
        for (int dr = -1; dr <= 1; ++dr)
            for (int dc = -1; dc <= 1; ++dc) {
                if (dr == 0 && dc == 0) continue;
                const int tr = tr0 + dr, tc = tc0 + dc;
                if ((unsigned)tr < 8u && (unsigned)tc < 8u)
                    nbl[n++] = (bi << 6) | (tr << 3) | tc;
            }
        nn_sh = n;
    }

    if (tid < 27) ksh[tid] = kern[tid];
    const float rho = rho_p[0];

    float m_[3][4], x_[3][4], r_[3][4], p_[3][4], q_[3][4], w_[3][4];
    #pragma unroll
    for (int c = 0; c < 3; ++c) {
        const float4 mv = *(const float4*)(mask + (bi * 3 + c) * HW + roffb);
        m_[c][0] = mv.x; m_[c][1] = mv.y; m_[c][2] = mv.z; m_[c][3] = mv.w;
    }

    // m_ring + iteration-invariant ring -> neighbor-strip index table
    for (int t = tid; t < 272; t += TPB) {
        int eh, ew; ring_pos(t, eh, ew);
        const int gh = h0 + eh - 2, gw = w0 + ew - 2;
        const bool valid = (unsigned)gh < (unsigned)H && (unsigned)gw < (unsigned)W;
        int src = -1;
        if (valid) {
            const int tr = gh >> 5, tc = gw >> 5;
            const int Tn = (bi << 6) | (tr << 3) | tc;
            const int lh = gh & 31, lw = gw & 31;
            int idx;
            if (tr != (h0 >> 5)) idx = (lh >= 30) ? 64 + (lh - 30) * 32 + lw : lh * 32 + lw;
            else                 idx = (lw >= 30) ? 192 + lh * 2 + (lw - 30) : 128 + lh * 2 + lw;
            src = Tn * STRIP_F + idx;
        }
        ringsrc[t] = src;
        #pragma unroll
        for (int c = 0; c < 3; ++c) {
            m_ring[c][t] = valid ? mask[(bi * 3 + c) * HW + gh * W + gw] : 0.f;
            r_ring[c][t] = 0.f;
            q_ring[c][t] = 0.f;
            u_ring[c][t] = 0.f;
        }
    }

    // ---- I-a: fill dext from y
    for (int e = tid; e < 1296; e += TPB) {
        const int eh = e / 36, ew = e - eh * 36;
        const int gh = h0 + eh - 2, gw = w0 + ew - 2;
        dext[e] = ((unsigned)gh < (unsigned)H && (unsigned)gw < (unsigned)W)
                      ? y[bi * HW + gh * W + gw] : 0.f;
    }
    __syncthreads();

    // ---- composite tables
    if (tid < 25) {
        const int A = tid / 5, Bq = tid % 5;
        float s = 0.f;
        for (int o = 0; o < 3; ++o)
            for (int i = (A > 2 ? A - 2 : 0); i <= (A < 2 ? A : 2); ++i)
                for (int j = (Bq > 2 ? Bq - 2 : 0); j <= (Bq < 2 ? Bq : 2); ++j)
                    s += ksh[o * 9 + (A - i) * 3 + (Bq - j)] * ksh[o * 9 + (2 - i) * 3 + (2 - j)];
        K2sh[tid] = s;
    } else if (tid < 35) {
        const int Bq = (tid - 25) % 5;
        const int krow = (tid < 30) ? 6 : 0;
        float s = 0.f;
        for (int o = 0; o < 3; ++o)
            for (int j = (Bq > 2 ? Bq - 2 : 0); j <= (Bq < 2 ? Bq : 2); ++j)
                s += ksh[o * 9 + krow + (Bq - j)] * ksh[o * 9 + krow + (2 - j)];
        if (tid < 30) Ctop[Bq] = s; else Cbot[Bq] = s;
    } else if (tid < 65) {
        const int u = tid - 35;
        const int side = u / 15;
        const int v = (u % 15) / 5;
        const int A = u % 5;
        const int kcol = side ? 0 : 2;
        int ilo = (A > 2 ? A - 2 : 0), ihi = (A < 2 ? A : 2);
        if (v == 1 && ilo < 1) ilo = 1;
        if (v == 2 && ihi > 1) ihi = 1;
        float s = 0.f;
        for (int o = 0; o < 3; ++o)
            for (int i = ilo; i <= ihi; ++i)
                s += ksh[o * 9 + (A - i) * 3 + kcol] * ksh[o * 9 + (2 - i) * 3 + kcol];
        float* dst = side ? (v == 0 ? CRf : v == 1 ? CRt : CRb)
                          : (v == 0 ? CLf : v == 1 ? CLt : CLb);
        dst[A] = s;
    }
    __syncthreads();

#define STAGE_BORDER(SRC)                                                          \
    _Pragma("unroll")                                                              \
    for (int c = 0; c < 3; ++c) {                                                  \
        if (row < 2) {                                                             \
            _Pragma("unroll")                                                      \
            for (int cc = 0; cc < 4; ++cc)                                         \
                sstage[c * 256 + row * 32 + wb + cc] = SRC[c][cc];                 \
        }                                                                          \
        if (row >= 30) {                                                           \
            _Pragma("unroll")                                                      \
            for (int cc = 0; cc < 4; ++cc)                                         \
                sstage[c * 256 + 64 + (row - 30) * 32 + wb + cc] = SRC[c][cc];     \
        }                                                                          \
        if (wb == 0)  { sstage[c * 256 + 128 + row * 2]     = SRC[c][0];           \
                        sstage[c * 256 + 128 + row * 2 + 1] = SRC[c][1]; }         \
        if (wb == 28) { sstage[c * 256 + 192 + row * 2]     = SRC[c][2];           \
                        sstage[c * 256 + 192 + row * 2 + 1] = SRC[c][3]; }         \
    }

    // I-a: b = m*PT(P(y)) + rho*(z-bet); x = b; publish b -> buf0
    {
        const float4 qv = conv_k2(dext, row, wb, h0, w0, K2sh, Ctop, Cbot,
                                  CLf, CLt, CLb, CRf, CRt, CRb);
        const float qa[4] = {qv.x, qv.y, qv.z, qv.w};
        #pragma unroll
        for (int c = 0; c < 3; ++c) {
            const int gi = (bi * 3 + c) * HW + roffb;
            const float4 zv = *(const float4*)(z + gi);
            const float4 bv = *(const float4*)(bet + gi);
            const float zz[4] = {zv.x, zv.y, zv.z, zv.w};
            const float bb[4] = {bv.x, bv.y, bv.z, bv.w};
            #pragma unroll
            for (int cc = 0; cc < 4; ++cc)
                x_[c][cc] = m_[c][cc] * qa[cc] + rho * (zz[cc] - bb[cc]);
        }
    }
    STAGE_BORDER(x_)
    __syncthreads();
    for (int t = tid; t < STRIP_F; t += TPB)
        ST_AG(strip + T * STRIP_F + t, sstage[t]);

    // finish population count -> xn, ng (opaque RMW polls)
    if (tid == 0) {
        while (__hip_atomic_fetch_add(cu + 144, opq0u(), __ATOMIC_RELAXED,
                                      __HIP_MEMORY_SCOPE_AGENT) < (unsigned)NBLK)
            __builtin_amdgcn_s_sleep(32);
        ng = 0;
        #pragma unroll
        for (int i = 0; i < 8; ++i) {
            unsigned c = __hip_atomic_fetch_add(cu + 160 + 16 * i, opq0u(),
                             __ATOMIC_RELAXED, __HIP_MEMORY_SCOPE_AGENT);
            ng += (c > 0u);
        }
        xn = __hip_atomic_fetch_add(cu + 160 + 16 * my_xcc, opq0u(),
                 __ATOMIC_RELAXED, __HIP_MEMORY_SCOPE_AGENT);
    }
    unsigned rnd = 1;
    frb2_wait(frb2_arrive(0.f, 0.f, rnd, ctrl, my_xcc, xn, ng), rnd, ctrl, my_xcc);
    rnd++;                                            // b strips visible

    // ---- I-b: d0 = sum m*b; r0 = b - A(b); gamma0; publish r0 -> buf1
    {
        float* dp = dext + (row + 2) * 36 + 2 + wb;
        #pragma unroll
        for (int cc = 0; cc < 4; ++cc)
            dp[cc] = m_[0][cc] * x_[0][cc] + m_[1][cc] * x_[1][cc] + m_[2][cc] * x_[2][cc];
    }
    for (int t = tid; t < 272; t += TPB) {
        int eh, ew; ring_pos(t, eh, ew);
        const int src = ringsrc[t];
        float s = 0.f;
        if (src >= 0) {
            #pragma unroll
            for (int c = 0; c < 3; ++c)
                s += m_ring[c][t] * LD_AG(strip + src + c * 256);
        }
        dext[eh * 36 + ew] = s;
    }
    __syncthreads();
    float gsum0 = 0.f;
    {
        const float4 qv = conv_k2(dext, row, wb, h0, w0, K2sh, Ctop, Cbot,
                                  CLf, CLt, CLb, CRf, CRt, CRb);
        const float qa[4] = {qv.x, qv.y, qv.z, qv.w};
        #pragma unroll
        for (int c = 0; c < 3; ++c)
            #pragma unroll
            for (int cc = 0; cc < 4; ++cc) {
                const float b = x_[c][cc];
                const float rv = b - (rho * b + m_[c][cc] * qa[cc]);
                r_[c][cc] = rv; p_[c][cc] = rv;
                gsum0 += rv * rv;
            }
    }
    STAGE_BORDER(r_)
    __syncthreads();
    for (int t = tid; t < STRIP_F; t += TPB)
        ST_AG(strip + STRIPBUF + T * STRIP_F + t, sstage[t]);

    float gamma = frb2_wait(frb2_arrive(gsum0, 0.f, rnd, ctrl, my_xcc, xn, ng),
                            rnd, ctrl, my_xcc).x;
    rnd++;                                            // r0 strips visible

    // r_ring <- r0 halo
    for (int t = tid; t < 272; t += TPB) {
        const int src = ringsrc[t];
        if (src >= 0) {
            #pragma unroll
            for (int c = 0; c < 3; ++c)
                r_ring[c][t] = LD_AG(strip + STRIPBUF + src + c * 256);
        }
    }

    // ---- I-c: w0 = A(r0); delta0 = r0.w0; q = w0; publish w0 -> buf0
    {
        float* dp = dext + (row + 2) * 36 + 2 + wb;
        #pragma unroll
        for (int cc = 0; cc < 4; ++cc)
            dp[cc] = m_[0][cc] * r_[0][cc] + m_[1][cc] * r_[1][cc] + m_[2][cc] * r_[2][cc];
    }
    for (int t = tid; t < 272; t += TPB) {
        int eh, ew; ring_pos(t, eh, ew);
        float s = 0.f;
        #pragma unroll
        for (int c = 0; c < 3; ++c) s += m_ring[c][t] * r_ring[c][t];
        dext[eh * 36 + ew] = s;
    }
    __syncthreads();
    float dsum0 = 0.f;
    {
        const float4 qv = conv_k2(dext, row, wb, h0, w0, K2sh, Ctop, Cbot,
                                  CLf, CLt, CLb, CRf, CRt, CRb);
        const float qa[4] = {qv.x, qv.y, qv.z, qv.w};
        #pragma unroll
        for (int c = 0; c < 3; ++c)
            #pragma unroll
            for (int cc = 0; cc < 4; ++cc) {
                const float wv = rho * r_[c][cc] + m_[c][cc] * qa[cc];
                q_[c][cc] = wv;
                dsum0 += r_[c][cc] * wv;
            }
    }
    STAGE_BORDER(q_)
    __syncthreads();
    for (int t = tid; t < STRIP_F; t += TPB)
        ST_AG(strip + T * STRIP_F + t, sstage[t]);

    const float delta0 = frb2_wait(frb2_arrive(dsum0, 0.f, rnd, ctrl, my_xcc, xn, ng),
                                   rnd, ctrl, my_xcc).x;
    rnd++;                                            // w0 strips visible

    // q_ring <- w0 halo
    for (int t = tid; t < 272; t += TPB) {
        const int src = ringsrc[t];
        if (src >= 0) {
            #pragma unroll
            for (int c = 0; c < 3; ++c)
                q_ring[c][t] = LD_AG(strip + src + c * 256);
        }
    }
    float alpha = (gamma >= TOL) ? (gamma / delta0) : 0.f;

    // ---- CG loop: ONE frb2 per iteration (Chronopoulos-Gear CG, R10 math).
    // beta = gamma'/gamma (both MEASURED); halo gather of w strips moved into
    // the frb2 wait shadow via neighbor flags (R12's verified-sound piece).
    for (int j = 0; j < NITER; ++j) {
        const bool active = (gamma >= TOL);

        if (active) {
            #pragma unroll
            for (int c = 0; c < 3; ++c)
                #pragma unroll
                for (int cc = 0; cc < 4; ++cc) {
                    x_[c][cc] += alpha * p_[c][cc];
                    r_[c][cc] -= alpha * q_[c][cc];
                }
            for (int t = tid; t < 272; t += TPB) {
                #pragma unroll
                for (int c = 0; c < 3; ++c)
                    r_ring[c][t] -= alpha * q_ring[c][t];
            }
        }

        // w = A(r): d = sum m*r (core + ring)
        {
            float* dp = dext + (row + 2) * 36 + 2 + wb;
            #pragma unroll
            for (int cc = 0; cc < 4; ++cc)
                dp[cc] = m_[0][cc] * r_[0][cc] + m_[1][cc] * r_[1][cc] + m_[2][cc] * r_[2][cc];
        }
        for (int t = tid; t < 272; t += TPB) {
            int eh, ew; ring_pos(t, eh, ew);
            float s = 0.f;
            #pragma unroll
            for (int c = 0; c < 3; ++c) s += m_ring[c][t] * r_ring[c][t];
            dext[eh * 36 + ew] = s;
        }
        __syncthreads();
        float gsum = 0.f, dsum = 0.f;
        {
            const float4 qv = conv_k2(dext, row, wb, h0, w0, K2sh, Ctop, Cbot,
                                      CLf, CLt, CLb, CRf, CRt, CRb);
            const float qa[4] = {qv.x, qv.y, qv.z, qv.w};
            #pragma unroll
            for (int c = 0; c < 3; ++c)
                #pragma unroll
                for (int cc = 0; cc < 4; ++cc) {
                    const float rv = r_[c][cc];
                    const float wv = rho * rv + m_[c][cc] * qa[cc];
                    w_[c][cc] = wv;
                    gsum += rv * rv;
                    dsum += rv * wv;
                }
        }
        // publish w strips, then arrive (drains stores), then flag + gather
        // in the wait shadow.
        STAGE_BORDER(w_)
        __syncthreads();
        const unsigned par = (unsigned)((j + 1) & 1);
        float* gb = strip + par * STRIPBUF;
        for (int t = tid; t < STRIP_F; t += TPB)
            ST_AG(gb + T * STRIP_F + t, sstage[t]);

        FrbTok tk = frb2_arrive(gsum, dsum, rnd, ctrl, my_xcc, xn, ng);

        if (tid == 0)
            __hip_atomic_store(flg + (par * 256 + T) * 8,
                               ((ull)rnd << 32) | 1ull,
                               __ATOMIC_RELAXED, __HIP_MEMORY_SCOPE_AGENT);
        if (tid < nn_sh) {
            ull* f = flg + (par * 256 + nbl[tid]) * 8;
            for (;;) {
                ull pk = __hip_atomic_fetch_add(f, opq0ull(),
                             __ATOMIC_RELAXED, __HIP_MEMORY_SCOPE_AGENT);
                if ((unsigned)(pk >> 32) >= rnd) break;
                __builtin_amdgcn_s_sleep(1);
            }
        }
        __syncthreads();
        for (int t = tid; t < 272; t += TPB) {        // gather w halo early
            const int src = ringsrc[t];
            if (src >= 0) {
                #pragma unroll
                for (int c = 0; c < 3; ++c)
                    u_ring[c][t] = LD_AG(gb + src + c * 256);
            }
        }

        const float2 gd = frb2_wait(tk, rnd, ctrl, my_xcc);
        rnd++;

        if (active) {
            const float gp = gd.x, dp = gd.y;
            const float beta = gp / gamma;
            const float alphan = gp / (dp - beta * gp / alpha);
            #pragma unroll
            for (int c = 0; c < 3; ++c)
                #pragma unroll
                for (int cc = 0; cc < 4; ++cc) {
                    p_[c][cc] = r_[c][cc] + beta * p_[c][cc];
                    q_[c][cc] = w_[c][cc] + beta * q_[c][cc];
                }
            for (int t = tid; t < 272; t += TPB) {
                if (ringsrc[t] >= 0) {
                    #pragma unroll
                    for (int c = 0; c < 3; ++c)
                        q_ring[c][t] = u_ring[c][t] + beta * q_ring[c][t];
                }
            }
            gamma = gp;
            alpha = alphan;
        }
    }

    #pragma unroll
    for (int c = 0; c < 3; ++c)
        *(float4*)(x_out + (bi * 3 + c) * HW + roffb) =
            make_float4(x_[c][0], x_[c][1], x_[c][2], x_[c][3]);
}

extern "C" void kernel_launch(void* const* d_in, const int* in_sizes, int n_in,
                              void* d_out, int out_size, void* d_ws, size_t ws_size,
                              hipStream_t stream)
{
    const float* mask = (const float*)d_in[0];
    const float* y    = (const float*)d_in[1];
    const float* z    = (const float*)d_in[2];
    const float* bet  = (const float*)d_in[3];
    const float* rho  = (const float*)d_in[4];
    const float* kern = (const float*)d_in[5];
    float* x  = (float*)d_out;
    float* ws = (float*)d_ws;

    hipMemsetAsync(ws + WS_CTRL, 0, CTRL_F * sizeof(float), stream);

    void* args[] = { (void*)&mask, (void*)&y, (void*)&z, (void*)&bet,
                     (void*)&rho, (void*)&kern, (void*)&x, (void*)&ws };
    hipLaunchCooperativeKernel((void*)cg_persistent, dim3(NBLK), dim3(TPB),
                               args, 0, stream);
}